// Round 1
// baseline (84.776 us; speedup 1.0000x reference)
//
#include <hip/hip_runtime.h>

#define NJ 21
#define NPAIR 210
#define TPB 128     // threads per block == samples per block
#define ROWF 63     // floats per sample row

// Parent index table (JOINTS alphabetical order), root Hip=3 has PAR[3]=3
constexpr int PAR_[NJ] = {3,0,12,3,11,7,4,9,1,3,5,8,1,20,16,13,18,1,3,14,17};

constexpr int depth_of(int x){ int d=0; while(PAR_[x]!=x){ x=PAR_[x]; ++d; } return d; }
constexpr int lca_of(int u,int v){
  int du=depth_of(u), dv=depth_of(v);
  while(du>dv){ u=PAR_[u]; --du; }
  while(dv>du){ v=PAR_[v]; --dv; }
  while(u!=v){ u=PAR_[u]; v=PAR_[v]; }
  return u;
}

struct PairTab { unsigned char u[NPAIR], v[NPAIR], L[NPAIR]; };
constexpr PairTab make_pairs(){
  PairTab t{};
  int k=0;
  for(int u=0;u<NJ;++u) for(int v=u+1;v<NJ;++v){
    t.u[k]=(unsigned char)u; t.v[k]=(unsigned char)v;
    t.L[k]=(unsigned char)lca_of(u,v); ++k;
  }
  return t;
}
constexpr PairTab PT = make_pairs();

// Topological order (every node's parent appears earlier)
constexpr int TOPO_[NJ] = {3,0,1,12,2,8,11,4,6,17,20,13,15,9,7,5,10,18,16,14,19};
// Parent-for-G: PAR with root mapped to virtual node 21 whose a == 0
constexpr int PV_[NJ]   = {3,0,12,21,11,7,4,9,1,3,5,8,1,20,16,13,18,1,3,14,17};

__global__ __launch_bounds__(TPB, 1)
void comp_loss_kernel(const float* __restrict__ in, const float* __restrict__ tg,
                      float* __restrict__ out, float invB)
{
  __shared__ float sIn[TPB*ROWF];   // 32256 B
  __shared__ float sTg[TPB*ROWF];   // 32256 B
  const int tid = threadIdx.x;
  const long long blockBase = (long long)blockIdx.x * (TPB*ROWF);

  // ---- coalesced global -> LDS staging (float4; block base is 16B-aligned) ----
  {
    const float4* gi = (const float4*)(in + blockBase);
    const float4* gt = (const float4*)(tg + blockBase);
    float4* si = (float4*)sIn;
    float4* st = (float4*)sTg;
    constexpr int N4 = TPB*ROWF/4;  // 2016
    for (int i = tid; i < N4; i += TPB){ si[i]=gi[i]; st[i]=gt[i]; }
  }
  __syncthreads();

  // ---- per-thread: pull own row into registers (stride 63 -> 2-way bank alias, free) ----
  float bn[ROWF], tt[ROWF];
  {
    const float* r  = sIn + tid*ROWF;
    const float* r2 = sTg + tid*ROWF;
    #pragma unroll
    for(int k=0;k<ROWF;++k) bn[k]=r[k];
    #pragma unroll
    for(int k=0;k<ROWF;++k) tt[k]=r2[k];
  }

  // ---- cumulative positions a[22][3]; a[21]=0 is the virtual root-parent ----
  float A[66];
  #pragma unroll
  for(int c=0;c<3;++c) A[63+c] = 0.f;
  #pragma unroll
  for(int i=0;i<NJ;++i){
    constexpr auto T = TOPO_;
    const int j = T[i];
    const int p = PAR_[j];
    #pragma unroll
    for(int c=0;c<3;++c)
      A[j*3+c] = (j==3) ? bn[j*3+c] : (bn[j*3+c] + A[p*3+c]);
  }

  // ---- F[j] = a[j]-tg[j]; G[j] = a[pv(j)]-tg[j] ----
  float F[ROWF], G[ROWF];
  #pragma unroll
  for(int j=0;j<NJ;++j){
    const int p = PV_[j];
    #pragma unroll
    for(int c=0;c<3;++c){
      F[j*3+c] = A[j*3+c] - tt[j*3+c];
      G[j*3+c] = A[p*3+c] - tt[j*3+c];
    }
  }

  // ---- pair loop, fully unrolled, all indices compile-time ----
  float acc = 0.f;
  #pragma unroll
  for(int p=0;p<NPAIR;++p){
    const int u = PT.u[p], v = PT.v[p], L = PT.L[p];
    #pragma unroll
    for(int c=0;c<3;++c){
      const float d = F[u*3+c] - G[v*3+c] - bn[L*3+c];
      acc += fabsf(d);   // folds to v_add_f32 with |src| modifier
    }
  }

  // ---- reduce: wave shuffle -> LDS -> one pre-scaled atomic per block ----
  #pragma unroll
  for(int off=32; off>0; off>>=1) acc += __shfl_down(acc, off, 64);
  __syncthreads();                       // done reading sIn; safe to reuse
  if ((tid & 63) == 0) sIn[tid>>6] = acc;
  __syncthreads();
  if (tid == 0){
    float bs = 0.f;
    #pragma unroll
    for(int w=0; w<TPB/64; ++w) bs += sIn[w];
    atomicAdd(out, bs * invB);           // block partial ~2.5 -> fp32-safe
  }
}

extern "C" void kernel_launch(void* const* d_in, const int* in_sizes, int n_in,
                              void* d_out, int out_size, void* d_ws, size_t ws_size,
                              hipStream_t stream) {
  const float* in = (const float*)d_in[0];
  const float* tg = (const float*)d_in[1];
  float* out = (float*)d_out;
  const int B = in_sizes[0] / (NJ*3);    // 65536
  // harness re-poisons d_out to 0xAA before every timed launch -> zero it ourselves
  hipMemsetAsync(out, 0, out_size * sizeof(float), stream);
  const int grid = B / TPB;              // 512 blocks (B is a multiple of 128)
  comp_loss_kernel<<<grid, TPB, 0, stream>>>(in, tg, out, 1.0f/(float)B);
}